// Round 6
// baseline (124.408 us; speedup 1.0000x reference)
//
#include <hip/hip_runtime.h>

#define TIMESTEPS 32
#define U 3   // float4s per thread; 37632/(256*3) = 49 blocks/image -> 1568 blocks (6.125/CU)

typedef float vfloat4 __attribute__((ext_vector_type(4)));

// NT stores (R4's +10% win: bypass L2 write-allocate) + t-OUTER burst ordering:
// each block owns 768 contiguous float4s (12KB) of one image; per t it emits
// 12KB of back-to-back stores before moving to the next plane. R2 showed
// ordering was irrelevant THROUGH L2; this retests it on the direct-to-HBM
// NT path where DRAM row locality can matter. U=3 fixes R2's 2.375-blocks/CU
// tail imbalance (now 6.125/CU, ~2% tail).
__global__ __launch_bounds__(256) void LatencyCoding_kernel(
    const float* __restrict__ x, float* __restrict__ out, int spatial4) {

    int b = blockIdx.y;
    int base4 = blockIdx.x * (256 * U) + threadIdx.x;

    const vfloat4* in4 = reinterpret_cast<const vfloat4*>(x) + (size_t)b * spatial4;

    unsigned m[U][4];
#pragma unroll
    for (int i = 0; i < U; ++i) {
        int s4 = base4 + i * 256;                       // always < spatial4 (exact tiling)
        vfloat4 v = __builtin_nontemporal_load(in4 + s4);
#pragma unroll
        for (int j = 0; j < 4; ++j) {
            float xn = fminf(fmaxf(v[j], 0.0f), 1.0f);  // clip(x,0,1)
            int l = (int)((1.0f - xn) * 31.0f);         // trunc, same fp32 ops as ref
            l = min(max(l, 0), TIMESTEPS - 1);
            m[i][j] = (xn > 0.0f) ? (1u << l) : 0u;     // one-hot time mask
        }
    }

    vfloat4* outb = reinterpret_cast<vfloat4*>(out)
                  + (size_t)b * TIMESTEPS * spatial4 + base4;

    for (int t = 0; t < TIMESTEPS; ++t) {
        vfloat4* outp = outb + (size_t)t * spatial4;
#pragma unroll
        for (int i = 0; i < U; ++i) {
            vfloat4 o;
            o.x = ((m[i][0] >> t) & 1u) ? 1.0f : 0.0f;
            o.y = ((m[i][1] >> t) & 1u) ? 1.0f : 0.0f;
            o.z = ((m[i][2] >> t) & 1u) ? 1.0f : 0.0f;
            o.w = ((m[i][3] >> t) & 1u) ? 1.0f : 0.0f;
            __builtin_nontemporal_store(o, outp + i * 256);
        }
    }
}

extern "C" void kernel_launch(void* const* d_in, const int* in_sizes, int n_in,
                              void* d_out, int out_size, void* d_ws, size_t ws_size,
                              hipStream_t stream) {
    const float* x   = (const float*)d_in[0];
    float*       out = (float*)d_out;

    int n = in_sizes[0];            // 32*3*224*224 = 4,816,896
    int B = 32;
    int spatial4 = (n / B) / 4;     // 37,632 = 256 * 147

    dim3 block(256, 1, 1);
    int gx = spatial4 / (256 * U);  // 49 (exact)
    dim3 grid(gx, B, 1);            // 49 x 32 = 1568 blocks

    LatencyCoding_kernel<<<grid, block, 0, stream>>>(x, out, spatial4);
}

// Round 7
// 115.527 us; speedup vs baseline: 1.0769x; 1.0769x over previous
//
#include <hip/hip_runtime.h>

#define TIMESTEPS 32

typedef float vfloat4 __attribute__((ext_vector_type(4)));

// R4 (best, 110.2us) + per-wave burst widening, keeping the proven t-INNER
// schedule. Each thread owns 2 float4s spaced 64 apart so each WAVE writes a
// contiguous 2KB per plane (two back-to-back dwordx4 bursts) instead of R4's
// 1KB -- doubling per-row-activate transfer on the NT->HBM path. Loop order,
// NT stores, and plain input loads unchanged from R4. 37632 = 294*128, so a
// thread's two float4s never cross an image boundary; 2352 blocks exactly.
__global__ __launch_bounds__(256) void LatencyCoding_kernel(
    const float* __restrict__ x, float* __restrict__ out,
    int spatial4 /* float4s per image */) {

    int g = blockIdx.x * blockDim.x + threadIdx.x;
    int W = g >> 6;                       // global wave id
    int l = g & 63;                       // lane
    int s4a = W * 128 + l;                // first float4 (wave covers [W*128, W*128+128))
    // second float4 = s4a + 64

    const vfloat4* in4 = reinterpret_cast<const vfloat4*>(x);
    vfloat4 va = in4[s4a];
    vfloat4 vb = in4[s4a + 64];

    int b  = s4a / spatial4;              // image index (same for both float4s)
    int s4 = s4a - b * spatial4;          // offset within image

    unsigned ma[4], mb[4];
#pragma unroll
    for (int j = 0; j < 4; ++j) {
        float xa = fminf(fmaxf(va[j], 0.0f), 1.0f);   // clip(x,0,1)
        int la = (int)((1.0f - xa) * 31.0f);          // trunc, same fp32 ops as ref
        la = min(max(la, 0), TIMESTEPS - 1);
        ma[j] = (xa > 0.0f) ? (1u << la) : 0u;

        float xb = fminf(fmaxf(vb[j], 0.0f), 1.0f);
        int lb = (int)((1.0f - xb) * 31.0f);
        lb = min(max(lb, 0), TIMESTEPS - 1);
        mb[j] = (xb > 0.0f) ? (1u << lb) : 0u;
    }

    vfloat4* out4 = reinterpret_cast<vfloat4*>(out)
                  + (size_t)b * TIMESTEPS * spatial4 + s4;

#pragma unroll
    for (int t = 0; t < TIMESTEPS; ++t) {
        vfloat4* outp = out4 + (size_t)t * spatial4;
        vfloat4 oa, ob;
        oa.x = ((ma[0] >> t) & 1u) ? 1.0f : 0.0f;
        oa.y = ((ma[1] >> t) & 1u) ? 1.0f : 0.0f;
        oa.z = ((ma[2] >> t) & 1u) ? 1.0f : 0.0f;
        oa.w = ((ma[3] >> t) & 1u) ? 1.0f : 0.0f;
        ob.x = ((mb[0] >> t) & 1u) ? 1.0f : 0.0f;
        ob.y = ((mb[1] >> t) & 1u) ? 1.0f : 0.0f;
        ob.z = ((mb[2] >> t) & 1u) ? 1.0f : 0.0f;
        ob.w = ((mb[3] >> t) & 1u) ? 1.0f : 0.0f;
        __builtin_nontemporal_store(oa, outp);
        __builtin_nontemporal_store(ob, outp + 64);
    }
}

extern "C" void kernel_launch(void* const* d_in, const int* in_sizes, int n_in,
                              void* d_out, int out_size, void* d_ws, size_t ws_size,
                              hipStream_t stream) {
    const float* x   = (const float*)d_in[0];
    float*       out = (float*)d_out;

    int n = in_sizes[0];            // 32*3*224*224 = 4,816,896
    int B = 32;
    int spatial4 = (n / B) / 4;     // 37,632 = 294 * 128
    int n4 = n / 4;                 // 1,204,224

    const int block = 256;
    int grid = n4 / (block * 2);    // 2352 exactly (each thread: 2 float4s)
    LatencyCoding_kernel<<<grid, block, 0, stream>>>(x, out, spatial4);
}

// Round 8
// 114.563 us; speedup vs baseline: 1.0859x; 1.0084x over previous
//
#include <hip/hip_runtime.h>

#define TIMESTEPS 32

typedef float vfloat4 __attribute__((ext_vector_type(4)));

// R4 (best, 110.2us = 5.77 TB/s) with exactly ONE change: per-wave plane-order
// stagger. Burst-size trend so far: 4KB block-plane bursts (R4,110) < 8KB
// (R6,115) < 12-32KB (R2/R5,124) -> finer interleave wins. This probes the
// finest extreme: wave w starts its t-loop at plane w&31, so at any instant
// consecutive waves write 1KB chunks of CONSECUTIVE planes, spreading the
// write front across all 1024 planes/banks instead of one plane-set at a time.
__global__ __launch_bounds__(256) void LatencyCoding_kernel(
    const float* __restrict__ x, float* __restrict__ out,
    int n4, int spatial4 /* float4s per image */) {

    int idx4 = blockIdx.x * blockDim.x + threadIdx.x;
    if (idx4 >= n4) return;

    vfloat4 v = reinterpret_cast<const vfloat4*>(x)[idx4];

    int b  = idx4 / spatial4;            // batch index
    int s4 = idx4 - b * spatial4;        // float4 offset within the image

    unsigned m[4];
#pragma unroll
    for (int j = 0; j < 4; ++j) {
        float xn = fminf(fmaxf(v[j], 0.0f), 1.0f);   // clip(x,0,1)
        int l = (int)((1.0f - xn) * 31.0f);          // trunc, same fp32 ops as ref
        l = min(max(l, 0), TIMESTEPS - 1);
        m[j] = (xn > 0.0f) ? (1u << l) : 0u;         // one-hot time mask
    }

    vfloat4* out4 = reinterpret_cast<vfloat4*>(out) + (size_t)b * TIMESTEPS * spatial4 + s4;

    int t0 = (idx4 >> 6) & 31;           // wave-id stagger: start plane differs per wave

#pragma unroll
    for (int k = 0; k < TIMESTEPS; ++k) {
        int t = (t0 + k) & (TIMESTEPS - 1);
        vfloat4 o;
        o.x = ((m[0] >> t) & 1u) ? 1.0f : 0.0f;
        o.y = ((m[1] >> t) & 1u) ? 1.0f : 0.0f;
        o.z = ((m[2] >> t) & 1u) ? 1.0f : 0.0f;
        o.w = ((m[3] >> t) & 1u) ? 1.0f : 0.0f;
        __builtin_nontemporal_store(o, out4 + (size_t)t * spatial4);
    }
}

extern "C" void kernel_launch(void* const* d_in, const int* in_sizes, int n_in,
                              void* d_out, int out_size, void* d_ws, size_t ws_size,
                              hipStream_t stream) {
    const float* x   = (const float*)d_in[0];
    float*       out = (float*)d_out;

    int n = in_sizes[0];            // 32*3*224*224 = 4,816,896
    int B = 32;
    int spatial4 = (n / B) / 4;     // 37,632
    int n4 = n / 4;                 // 1,204,224

    const int block = 256;
    int grid = (n4 + block - 1) / block;   // 4704 (exact)
    LatencyCoding_kernel<<<grid, block, 0, stream>>>(x, out, n4, spatial4);
}